// Round 15
// baseline (40.820 us; speedup 1.0000x reference)
//
#include <hip/hip_runtime.h>
#include <math.h>

// GaussianMixtureLoss: loss = CONST - mean_{b,n}( ln sum_m exp(p·g - |g|²/2) - |p|²/2 )
// B=4, N=4096, M=4096, D=3, SIGMA=1.
// R15: single worker kernel + 8-byte memset (was: worker + reduce kernel).
// Per-block ll -> ONE fp32 atomicAdd (1024 total, hidden under completion
// skew) + completion counter; last block writes out[0]. Inner loop, staging,
// and in-block tail are byte-identical to R14 (17.16us base).
#define BATCH 4
#define NPTS 4096
#define NMIX 4096
#define THREADS 256
#define PPB 16                // points per block
#define MSTAGE 2048           // mixtures staged per pass (1024 pairs, 32 KB)
#define PASSES (NMIX / MSTAGE)
#define JITER 16              // 64 pairs (128 mixtures) per wave-lane per j
#define NBLOCKS ((BATCH * NPTS) / PPB)  // 1024

#define LN2 0.6931471805599453f
#define CONST_TERM 0.9189385332046727f  // 0.5*log(2*pi)
#define INV_COUNT (1.0f / (float)(BATCH * NPTS))
// Schraudolph folded: K = 2^23*log2(e); BIAS = 2^23*(127-0.0563)
#define SEXP_K    12102203.0f
#define SEXP_BIAS 1.06488094e9f

typedef float v2f __attribute__((ext_vector_type(2)));

__device__ __forceinline__ float fast_log2(float x) {
#if __has_builtin(__builtin_amdgcn_logf)
  return __builtin_amdgcn_logf(x);
#else
  return log2f(x);
#endif
}

__device__ __forceinline__ v2f pk_fma(v2f a, v2f b, v2f c) {
  v2f d;
  asm("v_pk_fma_f32 %0, %1, %2, %3" : "=v"(d) : "v"(a), "v"(b), "v"(c));
  return d;
}

__global__ __launch_bounds__(THREADS) void gm_main(
    const float* __restrict__ pred, const float* __restrict__ gt,
    float* __restrict__ out, float* __restrict__ ws) {
  unsigned int* cnt = (unsigned int*)ws;   // ws[0]: completion counter
  float* tot = ws + 1;                     // ws[1]: loss accumulator

  __shared__ float4 gsh[MSTAGE];   // 32 KB (1024 pairs x 2 float4)
  __shared__ float wpart[64];      // [4 waves][16 cols]
  float* comb = (float*)gsh;       // aliased tail buffer [64][17]

  const int t = threadIdx.x;
  const int b = blockIdx.x >> 8;             // 256 blocks per batch
  const int n0 = (blockIdx.x & 255) * PPB;
  const int pl = t & 3;                      // point sub-group 0..3
  const int ml = t >> 2;                     // mixture-pair lane 0..63

  v2f px2[4], py2[4], pz2[4], acc[4];
#pragma unroll
  for (int k = 0; k < 4; ++k) {
    const float* p = pred + ((size_t)(b * NPTS + n0 + pl * 4 + k)) * 3;
    px2[k] = (v2f){p[0], p[0]};
    py2[k] = (v2f){p[1], p[1]};
    pz2[k] = (v2f){p[2], p[2]};
    acc[k] = (v2f){0.f, 0.f};
  }

  for (int q = 0; q < PASSES; ++q) {
    __syncthreads();  // prior-pass readers done
#pragma unroll
    for (int i = 0; i < 4; ++i) {
      int s = t + i * THREADS;  // pair index 0..1023
      const float2* g = (const float2*)(gt +
          ((size_t)(b * NMIX + q * MSTAGE + 2 * s)) * 3);
      float2 g01 = g[0], g23 = g[1], g45 = g[2];
      float n20 = fmaf(g01.x, g01.x, fmaf(g01.y, g01.y, g23.x * g23.x));
      float n21 = fmaf(g23.y, g23.y, fmaf(g45.x, g45.x, g45.y * g45.y));
      gsh[2 * s]     = make_float4(SEXP_K * g01.x, SEXP_K * g23.y,
                                   SEXP_K * g01.y, SEXP_K * g45.x);
      gsh[2 * s + 1] = make_float4(SEXP_K * g23.x, SEXP_K * g45.y,
                                   fmaf(n20, -0.5f * SEXP_K, SEXP_BIAS),
                                   fmaf(n21, -0.5f * SEXP_K, SEXP_BIAS));
    }
    __syncthreads();

#pragma unroll 4
    for (int j = 0; j < JITER; ++j) {
      int s = ml + 64 * j;
      float4 a = gsh[2 * s];      // {Kgx0,Kgx1,Kgy0,Kgy1}
      float4 c4 = gsh[2 * s + 1]; // {Kgz0,Kgz1,w0,w1}
      v2f gx2 = (v2f){a.x, a.y}, gy2 = (v2f){a.z, a.w};
      v2f gz2 = (v2f){c4.x, c4.y}, w2 = (v2f){c4.z, c4.w};
#pragma unroll
      for (int k = 0; k < 4; ++k) {
        v2f d = pk_fma(pz2[k], gz2, w2);
        d = pk_fma(py2[k], gy2, d);
        d = pk_fma(px2[k], gx2, d);
        acc[k].x += __builtin_bit_cast(float, (int)d.x);  // Schraudolph exp
        acc[k].y += __builtin_bit_cast(float, (int)d.y);
      }
    }
  }

  __syncthreads();  // all gsh reads done before aliasing as comb

#pragma unroll
  for (int k = 0; k < 4; ++k)
    comb[ml * (PPB + 1) + pl * 4 + k] = acc[k].x + acc[k].y;
  __syncthreads();

  {
    const int col = t & 15, grp = t >> 4;
    float s = 0.f;
#pragma unroll
    for (int r = 0; r < 4; ++r) s += comb[(grp * 4 + r) * (PPB + 1) + col];
    s += __shfl_down(s, 32, 64);
    s += __shfl_down(s, 16, 64);
    if ((t & 63) < 16) wpart[(t >> 6) * 16 + col] = s;
  }
  __syncthreads();

  float ll = 0.f;
  if (t < 16) {
    float s = wpart[t] + wpart[16 + t] + wpart[32 + t] + wpart[48 + t];
    const float* p = pred + ((size_t)(b * NPTS + n0 + t)) * 3;
    float hp2 = 0.5f * (p[0] * p[0] + p[1] * p[1] + p[2] * p[2]);
    ll = (LN2 * fast_log2(s) - hp2) * INV_COUNT;
#pragma unroll
    for (int off = 8; off > 0; off >>= 1) ll += __shfl_down(ll, off, 16);
  }

  // fused reduce: one atomic per block + completion counter; last block
  // (all 1024 adds visible) writes the final scalar.
  if (t == 0) {
    atomicAdd(tot, ll);
    __threadfence();
    unsigned int old = atomicAdd(cnt, 1u);
    if (old == NBLOCKS - 1) {
      __threadfence();
      float s = __hip_atomic_load(tot, __ATOMIC_RELAXED,
                                  __HIP_MEMORY_SCOPE_AGENT);
      out[0] = CONST_TERM - s;
    }
  }
}

extern "C" void kernel_launch(void* const* d_in, const int* in_sizes, int n_in,
                              void* d_out, int out_size, void* d_ws, size_t ws_size,
                              hipStream_t stream) {
  const float* pred = (const float*)d_in[0];
  const float* gt   = (const float*)d_in[1];
  float* out = (float*)d_out;
  float* ws = (float*)d_ws;

  hipMemsetAsync(d_ws, 0, 8, stream);  // counter + accumulator
  gm_main<<<NBLOCKS, THREADS, 0, stream>>>(pred, gt, out, ws);
}

// Round 16
// 16.980 us; speedup vs baseline: 2.4040x; 2.4040x over previous
//
#include <hip/hip_runtime.h>
#include <math.h>

// GaussianMixtureLoss: loss = CONST - mean_{b,n}( ln sum_m exp(p·g - |g|²/2) - |p|²/2 )
// B=4, N=4096, M=4096, D=3, SIGMA=1.
// R16: halve LDS-read traffic per exp. R14's inner loop is ds_read_b128
// THROUGHPUT bound (~12cyc/inst, m134): 2 reads per 8 exps = 5.1us/CU LDS
// occupancy. New map: thread = 8 points (pl=t&1) x 2 mixtures (ml=t>>1),
// so the same 32 B LDS read feeds 16 exps -> LDS 5.1 -> 2.6us, VALU issue
// (~3.2us) becomes the limiter. Staging/tail/2-dispatch = R14 (17.16 base).
// NO memset in graph (R15 lesson: in-graph fills cost ~39us).
#define BATCH 4
#define NPTS 4096
#define NMIX 4096
#define THREADS 256
#define PPB 16                // points per block
#define PTS 8                 // points per thread
#define MSTAGE 2048           // mixtures staged per pass (1024 pairs, 32 KB)
#define PASSES (NMIX / MSTAGE)
#define JITER 8               // 1024 pairs / 128 lanes per pass
#define NBLOCKS ((BATCH * NPTS) / PPB)  // 1024

#define LN2 0.6931471805599453f
#define CONST_TERM 0.9189385332046727f  // 0.5*log(2*pi)
#define INV_COUNT (1.0f / (float)(BATCH * NPTS))
// Schraudolph folded: K = 2^23*log2(e); BIAS = 2^23*(127-0.0563)
#define SEXP_K    12102203.0f
#define SEXP_BIAS 1.06488094e9f

typedef float v2f __attribute__((ext_vector_type(2)));

__device__ __forceinline__ float fast_log2(float x) {
#if __has_builtin(__builtin_amdgcn_logf)
  return __builtin_amdgcn_logf(x);
#else
  return log2f(x);
#endif
}

__device__ __forceinline__ v2f pk_fma(v2f a, v2f b, v2f c) {
  v2f d;
  asm("v_pk_fma_f32 %0, %1, %2, %3" : "=v"(d) : "v"(a), "v"(b), "v"(c));
  return d;
}

__global__ __launch_bounds__(THREADS) void gm_main(
    const float* __restrict__ pred, const float* __restrict__ gt,
    float* __restrict__ bsum) {
  __shared__ float4 gsh[MSTAGE];   // 32 KB (1024 pairs x 2 float4)
  __shared__ float wpart[64];      // [4 waves][16 cols]
  float* comb = (float*)gsh;       // aliased tail buffer [128][17]

  const int t = threadIdx.x;
  const int b = blockIdx.x >> 8;             // 256 blocks per batch
  const int n0 = (blockIdx.x & 255) * PPB;
  const int pl = t & 1;                      // point half 0..1 (8 pts each)
  const int ml = t >> 1;                     // mixture-pair lane 0..127

  // 8 scalar points, hoisted as broadcast pairs for pk_fma
  v2f px2[PTS], py2[PTS], pz2[PTS], acc[PTS];
#pragma unroll
  for (int k = 0; k < PTS; ++k) {
    const float* p = pred + ((size_t)(b * NPTS + n0 + pl * PTS + k)) * 3;
    px2[k] = (v2f){p[0], p[0]};
    py2[k] = (v2f){p[1], p[1]};
    pz2[k] = (v2f){p[2], p[2]};
    acc[k] = (v2f){0.f, 0.f};
  }

  for (int q = 0; q < PASSES; ++q) {
    __syncthreads();  // prior-pass readers done
#pragma unroll
    for (int i = 0; i < 4; ++i) {
      int s = t + i * THREADS;  // pair index 0..1023
      const float2* g = (const float2*)(gt +
          ((size_t)(b * NMIX + q * MSTAGE + 2 * s)) * 3);
      float2 g01 = g[0], g23 = g[1], g45 = g[2];
      // mixture 2s: (g01.x, g01.y, g23.x); 2s+1: (g23.y, g45.x, g45.y)
      float n20 = fmaf(g01.x, g01.x, fmaf(g01.y, g01.y, g23.x * g23.x));
      float n21 = fmaf(g23.y, g23.y, fmaf(g45.x, g45.x, g45.y * g45.y));
      gsh[2 * s]     = make_float4(SEXP_K * g01.x, SEXP_K * g23.y,
                                   SEXP_K * g01.y, SEXP_K * g45.x);
      gsh[2 * s + 1] = make_float4(SEXP_K * g23.x, SEXP_K * g45.y,
                                   fmaf(n20, -0.5f * SEXP_K, SEXP_BIAS),
                                   fmaf(n21, -0.5f * SEXP_K, SEXP_BIAS));
    }
    __syncthreads();

#pragma unroll 2
    for (int j = 0; j < JITER; ++j) {
      int s = ml + 128 * j;
      float4 a = gsh[2 * s];      // {Kgx0,Kgx1,Kgy0,Kgy1}
      float4 c4 = gsh[2 * s + 1]; // {Kgz0,Kgz1,w0,w1}
      v2f gx2 = (v2f){a.x, a.y}, gy2 = (v2f){a.z, a.w};
      v2f gz2 = (v2f){c4.x, c4.y}, w2 = (v2f){c4.z, c4.w};
#pragma unroll
      for (int k = 0; k < PTS; ++k) {
        v2f d = pk_fma(pz2[k], gz2, w2);
        d = pk_fma(py2[k], gy2, d);
        d = pk_fma(px2[k], gx2, d);
        acc[k].x += __builtin_bit_cast(float, (int)d.x);  // Schraudolph exp
        acc[k].y += __builtin_bit_cast(float, (int)d.y);
      }
    }
  }

  __syncthreads();  // all gsh reads done before aliasing as comb

  // comb[ml][pl*8+k]: both mixture halves pre-summed
#pragma unroll
  for (int k = 0; k < PTS; ++k)
    comb[ml * (PPB + 1) + pl * PTS + k] = acc[k].x + acc[k].y;
  __syncthreads();

  {
    const int col = t & 15, grp = t >> 4;  // 16 groups x 8 rows
    float s = 0.f;
#pragma unroll
    for (int r = 0; r < 8; ++r) s += comb[(grp * 8 + r) * (PPB + 1) + col];
    s += __shfl_down(s, 32, 64);
    s += __shfl_down(s, 16, 64);
    if ((t & 63) < 16) wpart[(t >> 6) * 16 + col] = s;
  }
  __syncthreads();

  if (t < 16) {
    float s = wpart[t] + wpart[16 + t] + wpart[32 + t] + wpart[48 + t];
    const float* p = pred + ((size_t)(b * NPTS + n0 + t)) * 3;
    float hp2 = 0.5f * (p[0] * p[0] + p[1] * p[1] + p[2] * p[2]);
    float ll = (LN2 * fast_log2(s) - hp2) * INV_COUNT;
#pragma unroll
    for (int off = 8; off > 0; off >>= 1) ll += __shfl_down(ll, off, 16);
    if (t == 0) bsum[blockIdx.x] = ll;
  }
}

__global__ __launch_bounds__(THREADS) void gm_reduce(
    const float* __restrict__ bsum, float* __restrict__ out) {
  const int t = threadIdx.x;
  float v = (bsum[t] + bsum[t + 256]) + (bsum[t + 512] + bsum[t + 768]);
  for (int off = 32; off > 0; off >>= 1) v += __shfl_down(v, off, 64);
  __shared__ float w[4];
  if ((t & 63) == 0) w[t >> 6] = v;
  __syncthreads();
  if (t == 0) out[0] = CONST_TERM - ((w[0] + w[1]) + (w[2] + w[3]));
}

extern "C" void kernel_launch(void* const* d_in, const int* in_sizes, int n_in,
                              void* d_out, int out_size, void* d_ws, size_t ws_size,
                              hipStream_t stream) {
  const float* pred = (const float*)d_in[0];
  const float* gt   = (const float*)d_in[1];
  float* out = (float*)d_out;
  float* bsum = (float*)d_ws;  // 1024 floats, fully overwritten every call

  gm_main<<<NBLOCKS, THREADS, 0, stream>>>(pred, gt, bsum);
  gm_reduce<<<1, THREADS, 0, stream>>>(bsum, out);
}

// Round 17
// 16.765 us; speedup vs baseline: 2.4349x; 1.0128x over previous
//
#include <hip/hip_runtime.h>
#include <math.h>

// GaussianMixtureLoss: loss = CONST - mean_{b,n}( ln sum_m exp(p·g - |g|²/2) - |p|²/2 )
// B=4, N=4096, M=4096, D=3, SIGMA=1.
// R17: halve block count (PPB 16->32, NBLOCKS 1024->512). Staging is
// per-block-fixed (~96KB L2 + ~200 inst/thread regardless of PPB), so
// halving blocks halves aggregate staging work + launch tail. Thread = 8
// points x 2 mixtures (same VGPR footprint as R16); packed v2f accumulate
// (v_pk_add_f32 hoped) trims 1 inst / 2 exps. 2-dispatch, no memset.
#define BATCH 4
#define NPTS 4096
#define NMIX 4096
#define THREADS 256
#define PPB 32                // points per block
#define PTS 8                 // points per thread
#define MSTAGE 2048           // mixtures staged per pass (1024 pairs, 32 KB)
#define PASSES (NMIX / MSTAGE)
#define JITER 16              // 1024 pairs / 64 mixture-lanes per pass
#define NBLOCKS ((BATCH * NPTS) / PPB)  // 512

#define LN2 0.6931471805599453f
#define CONST_TERM 0.9189385332046727f  // 0.5*log(2*pi)
#define INV_COUNT (1.0f / (float)(BATCH * NPTS))
// Schraudolph folded: K = 2^23*log2(e); BIAS = 2^23*(127-0.0563)
#define SEXP_K    12102203.0f
#define SEXP_BIAS 1.06488094e9f

typedef float v2f __attribute__((ext_vector_type(2)));

__device__ __forceinline__ float fast_log2(float x) {
#if __has_builtin(__builtin_amdgcn_logf)
  return __builtin_amdgcn_logf(x);
#else
  return log2f(x);
#endif
}

__device__ __forceinline__ v2f pk_fma(v2f a, v2f b, v2f c) {
  v2f d;
  asm("v_pk_fma_f32 %0, %1, %2, %3" : "=v"(d) : "v"(a), "v"(b), "v"(c));
  return d;
}

__global__ __launch_bounds__(THREADS) void gm_main(
    const float* __restrict__ pred, const float* __restrict__ gt,
    float* __restrict__ bsum) {
  __shared__ float4 gsh[MSTAGE];   // 32 KB (1024 pairs x 2 float4)
  __shared__ float wpart[4][32];   // [wave][col]
  float* comb = (float*)gsh;       // aliased tail buffer [64][33]

  const int t = threadIdx.x;
  const int b = blockIdx.x >> 7;             // 128 blocks per batch
  const int n0 = (blockIdx.x & 127) * PPB;
  const int pl = t & 3;                      // point quarter (8 pts each)
  const int ml = t >> 2;                     // mixture-pair lane 0..63

  // 8 scalar points, hoisted as broadcast pairs for pk_fma
  v2f px2[PTS], py2[PTS], pz2[PTS], acc[PTS];
#pragma unroll
  for (int k = 0; k < PTS; ++k) {
    const float* p = pred + ((size_t)(b * NPTS + n0 + pl * PTS + k)) * 3;
    px2[k] = (v2f){p[0], p[0]};
    py2[k] = (v2f){p[1], p[1]};
    pz2[k] = (v2f){p[2], p[2]};
    acc[k] = (v2f){0.f, 0.f};
  }

  for (int q = 0; q < PASSES; ++q) {
    __syncthreads();  // prior-pass readers done
#pragma unroll
    for (int i = 0; i < 4; ++i) {
      int s = t + i * THREADS;  // pair index 0..1023
      const float2* g = (const float2*)(gt +
          ((size_t)(b * NMIX + q * MSTAGE + 2 * s)) * 3);
      float2 g01 = g[0], g23 = g[1], g45 = g[2];
      // mixture 2s: (g01.x, g01.y, g23.x); 2s+1: (g23.y, g45.x, g45.y)
      float n20 = fmaf(g01.x, g01.x, fmaf(g01.y, g01.y, g23.x * g23.x));
      float n21 = fmaf(g23.y, g23.y, fmaf(g45.x, g45.x, g45.y * g45.y));
      gsh[2 * s]     = make_float4(SEXP_K * g01.x, SEXP_K * g23.y,
                                   SEXP_K * g01.y, SEXP_K * g45.x);
      gsh[2 * s + 1] = make_float4(SEXP_K * g23.x, SEXP_K * g45.y,
                                   fmaf(n20, -0.5f * SEXP_K, SEXP_BIAS),
                                   fmaf(n21, -0.5f * SEXP_K, SEXP_BIAS));
    }
    __syncthreads();

#pragma unroll 2
    for (int j = 0; j < JITER; ++j) {
      int s = ml + 64 * j;
      float4 a = gsh[2 * s];      // {Kgx0,Kgx1,Kgy0,Kgy1}
      float4 c4 = gsh[2 * s + 1]; // {Kgz0,Kgz1,w0,w1}
      v2f gx2 = (v2f){a.x, a.y}, gy2 = (v2f){a.z, a.w};
      v2f gz2 = (v2f){c4.x, c4.y}, w2 = (v2f){c4.z, c4.w};
#pragma unroll
      for (int k = 0; k < PTS; ++k) {
        v2f d = pk_fma(pz2[k], gz2, w2);
        d = pk_fma(py2[k], gy2, d);
        d = pk_fma(px2[k], gx2, d);
        v2f e;                                    // Schraudolph exp, packed
        e.x = __builtin_bit_cast(float, (int)d.x);
        e.y = __builtin_bit_cast(float, (int)d.y);
        acc[k] += e;                              // v_pk_add_f32 hoped
      }
    }
  }

  __syncthreads();  // all gsh reads done before aliasing as comb

  // comb[ml][pl*8+k]: both mixture halves pre-summed; [64][33] padded
#pragma unroll
  for (int k = 0; k < PTS; ++k)
    comb[ml * (PPB + 1) + pl * PTS + k] = acc[k].x + acc[k].y;
  __syncthreads();

  {
    const int col = t & 31, grp = t >> 5;  // 8 groups x 8 rows
    float s = 0.f;
#pragma unroll
    for (int r = 0; r < 8; ++r) s += comb[(grp * 8 + r) * (PPB + 1) + col];
    // wave w covers grps {2w, 2w+1}: lanes 0-31 grp 2w, lanes 32-63 grp 2w+1
    s += __shfl_down(s, 32, 64);
    if ((t & 63) < 32) wpart[t >> 6][col] = s;
  }
  __syncthreads();

  if (t < 32) {
    float s = (wpart[0][t] + wpart[1][t]) + (wpart[2][t] + wpart[3][t]);
    const float* p = pred + ((size_t)(b * NPTS + n0 + t)) * 3;
    float hp2 = 0.5f * (p[0] * p[0] + p[1] * p[1] + p[2] * p[2]);
    float ll = (LN2 * fast_log2(s) - hp2) * INV_COUNT;
#pragma unroll
    for (int off = 16; off > 0; off >>= 1) ll += __shfl_down(ll, off, 32);
    if (t == 0) bsum[blockIdx.x] = ll;
  }
}

__global__ __launch_bounds__(THREADS) void gm_reduce(
    const float* __restrict__ bsum, float* __restrict__ out) {
  const int t = threadIdx.x;
  float v = bsum[t] + bsum[t + 256];  // 512 entries
  for (int off = 32; off > 0; off >>= 1) v += __shfl_down(v, off, 64);
  __shared__ float w[4];
  if ((t & 63) == 0) w[t >> 6] = v;
  __syncthreads();
  if (t == 0) out[0] = CONST_TERM - ((w[0] + w[1]) + (w[2] + w[3]));
}

extern "C" void kernel_launch(void* const* d_in, const int* in_sizes, int n_in,
                              void* d_out, int out_size, void* d_ws, size_t ws_size,
                              hipStream_t stream) {
  const float* pred = (const float*)d_in[0];
  const float* gt   = (const float*)d_in[1];
  float* out = (float*)d_out;
  float* bsum = (float*)d_ws;  // 512 floats, fully overwritten every call

  gm_main<<<NBLOCKS, THREADS, 0, stream>>>(pred, gt, bsum);
  gm_reduce<<<1, THREADS, 0, stream>>>(bsum, out);
}